// Round 18
// baseline (1191.397 us; speedup 1.0000x reference)
//
#include <hip/hip_runtime.h>
#include <math.h>

#define N_PROP 256
#define NUM_CLASS 80
#define H_FEAT 50
#define W_FEAT 80
#define K_DIM 200704        // 1024*14*14
#define D_HID 1024
#define SPATIAL_SCALE 0.0625f
#define SCALE_CLAMP 4.135166556742356f   // log(1000/16)
#define IMG_W_F 1280.0f
#define IMG_H_F 800.0f

typedef unsigned short ushort_t;
typedef __attribute__((ext_vector_type(8))) short short8v;       // 8 bf16 = 4 VGPR
typedef __attribute__((ext_vector_type(16))) float f32x16;       // 32x32 acc
typedef __attribute__((ext_vector_type(4))) float f32x4v;        // ext-vector float4
typedef __attribute__((ext_vector_type(4))) unsigned short ushort4v;
typedef __attribute__((ext_vector_type(2))) unsigned short ushort2v;

__device__ __forceinline__ unsigned short f2bf(float f) {
  unsigned int u = __builtin_bit_cast(unsigned int, f);
  u += 0x7FFFu + ((u >> 16) & 1u);                 // RNE
  return (unsigned short)(u >> 16);
}
__device__ __forceinline__ float bf2f(unsigned short h) {
  unsigned int u = ((unsigned int)h) << 16;
  return __builtin_bit_cast(float, u);
}

// ---------------- RoIAlign -> A as bf16 hi/lo planes (r13 verbatim) ----------------
__global__ void roi_kernel(const float* __restrict__ F, const float* __restrict__ props,
                           ushort_t* __restrict__ Ahi, ushort_t* __restrict__ Alo) {
  const int tid = threadIdx.x;
  const int m = blockIdx.y;
  const int cg = blockIdx.x;                 // channel group of 128
  __shared__ float w00[196], w01[196], w10[196], w11[196];
  __shared__ int o00[196], o01[196], o10[196], o11[196];
  const float x1s = props[m*4+0]*SPATIAL_SCALE;
  const float y1s = props[m*4+1]*SPATIAL_SCALE;
  const float x2s = props[m*4+2]*SPATIAL_SCALE;
  const float y2s = props[m*4+3]*SPATIAL_SCALE;
  const float bwf = fmaxf(x2s-x1s, 1.0f) / 14.0f;
  const float bhf = fmaxf(y2s-y1s, 1.0f) / 14.0f;
  if (tid < 196) {
    int ph = tid / 14, pw = tid - ph*14;
    float X = x1s + (pw + 0.5f)*bwf;
    float Y = y1s + (ph + 0.5f)*bhf;
    bool valid = (Y >= -1.0f) && (Y <= (float)H_FEAT) && (X >= -1.0f) && (X <= (float)W_FEAT);
    float x = fminf(fmaxf(X, 0.0f), (float)(W_FEAT-1));
    float y = fminf(fmaxf(Y, 0.0f), (float)(H_FEAT-1));
    float xf = floorf(x), yf = floorf(y);
    int ix0 = (int)xf, iy0 = (int)yf;
    int ix1 = min(ix0+1, W_FEAT-1), iy1 = min(iy0+1, H_FEAT-1);
    float lx = x-xf, ly = y-yf, hx = 1.0f-lx, hy = 1.0f-ly;
    float v = valid ? 1.0f : 0.0f;
    w00[tid] = hy*hx*v; w01[tid] = hy*lx*v; w10[tid] = ly*hx*v; w11[tid] = ly*lx*v;
    o00[tid] = iy0*W_FEAT+ix0; o01[tid] = iy0*W_FEAT+ix1;
    o10[tid] = iy1*W_FEAT+ix0; o11[tid] = iy1*W_FEAT+ix1;
  }
  __syncthreads();
  const int base_c = cg*128;
  const size_t rowbase = (size_t)m*K_DIM + (size_t)base_c*196;
  for (int it = 0; it < 49; ++it) {          // 128*196/(256*2)
    int i2 = it*512 + tid*2;                 // even; pair never crosses channel (196 even)
    int c = i2 / 196;
    int b = i2 - c*196;
    const float* f = F + (size_t)(base_c + c)*4000;
    float v0 = w00[b]*f[o00[b]] + w01[b]*f[o01[b]] + w10[b]*f[o10[b]] + w11[b]*f[o11[b]];
    float v1 = w00[b+1]*f[o00[b+1]] + w01[b+1]*f[o01[b+1]] + w10[b+1]*f[o10[b+1]] + w11[b+1]*f[o11[b+1]];
    unsigned short h0 = f2bf(v0), h1 = f2bf(v1);
    ushort2v hv; hv[0] = h0; hv[1] = h1;
    ushort2v lv; lv[0] = f2bf(v0 - bf2f(h0)); lv[1] = f2bf(v1 - bf2f(h1));
    *(ushort2v*)&Ahi[rowbase + i2] = hv;
    *(ushort2v*)&Alo[rowbase + i2] = lv;
  }
}

// ------- split-bf16 MFMA GEMM, 128x128 tile, 256 threads, 2-phase BK=16 pipeline -------
// 4 waves (2M x 2N), per-wave out 64x64 (acc 2x2 f32x16 = 64 VGPR) -> 3-4 blocks/CU.
// LDS: 2 buffers x 8192 ushorts (16KB each... 32KB total):
//   A: plane(2)*2048 + kb(2)*1024 + row(128)*8    (glds linear s*8, s=plane*256+kb*128+row)
//   B: 4096 + khalf(2)*1024 + scol(128)*8 (+2048 for lo), scol = col ^ ((col>>3)&7)
__global__ __launch_bounds__(256, 2) void mfma_gemm(
    const ushort_t* __restrict__ Ahi, const ushort_t* __restrict__ Alo,
    const float* __restrict__ B, float* __restrict__ P, int steps_per, int nwg) {
  __shared__ ushort_t lds[16384];
  const int tid = threadIdx.x;
  const int wv = tid >> 6, lane = tid & 63, l31 = lane & 31, lhi = lane >> 5;
  const int wm = wv >> 1, wn = wv & 1;       // 2M x 2N wave grid
  int id = blockIdx.x;
  int nid = ((nwg & 7) == 0) ? ((id & 7) * (nwg >> 3) + (id >> 3)) : id;
  const int mn = nid & 15;
  const int z  = nid >> 4;
  const int bm = (mn >> 3) * 128;
  const int bn = (mn & 7) * 128;
  const int step0 = z * steps_per;           // 32-k steps
  int steps = steps_per;
  if (step0 + steps > 6272) steps = 6272 - step0;   // may be <= 0

  f32x16 acc[2][2];
  #pragma unroll
  for (int a = 0; a < 2; ++a)
    #pragma unroll
    for (int b = 0; b < 2; ++b)
      #pragma unroll
      for (int e = 0; e < 16; ++e) acc[a][b][e] = 0.0f;

  if (steps > 0) {
    const int H = steps * 2;                 // 16-k halves
    // A glds: s = i*256 + tid in [0,512): plane=s>>8, kb=(s>>7)&1, row=s&127
    const ushort_t* asrc[2];
    #pragma unroll
    for (int i = 0; i < 2; ++i) {
      int s = i*256 + tid;
      int plane = s >> 8, kb = (s >> 7) & 1, row = s & 127;
      const ushort_t* basep = plane ? Alo : Ahi;
      asrc[i] = basep + (size_t)(bm + row) * K_DIM + step0*32 + kb*8;
    }
    // B staging: tid<128. p=tid>>5 (0..3): k-rows 4p..4p+3; c4=tid&31: cols 4c4..+3
    const int p = tid >> 5, c4 = tid & 31;
    const bool bstage = (tid < 128);
    const float* bsrc = B + (size_t)(step0*32 + 4*p) * D_HID + bn + c4*4;
    const unsigned bkh = (unsigned)(p >> 1) * 1024u, bsub = (unsigned)((p & 1) * 4);

    #define STAGE_A(bufn) do { \
      _Pragma("unroll") \
      for (int i = 0; i < 2; ++i) { \
        __builtin_amdgcn_global_load_lds(asrc[i], &lds[(bufn) + (unsigned)(i*256 + tid)*8u], 16, 0, 0); \
        asrc[i] += 16; } \
    } while (0)

    #define LOAD_B() do { \
      if (bstage) { \
        b0 = __builtin_nontemporal_load((const f32x4v*)(bsrc)); \
        b1 = __builtin_nontemporal_load((const f32x4v*)(bsrc + D_HID)); \
        b2 = __builtin_nontemporal_load((const f32x4v*)(bsrc + 2*D_HID)); \
        b3 = __builtin_nontemporal_load((const f32x4v*)(bsrc + 3*D_HID)); \
      } \
      bsrc += 16 * D_HID; \
    } while (0)

    #define WRITE_B(bufn) do { \
      if (bstage) { \
        _Pragma("unroll") \
        for (int cc = 0; cc < 4; ++cc) { \
          float g0 = b0[cc], g1 = b1[cc], g2 = b2[cc], g3 = b3[cc]; \
          ushort4v hv, lv; \
          hv[0]=f2bf(g0); lv[0]=f2bf(g0-bf2f(hv[0])); \
          hv[1]=f2bf(g1); lv[1]=f2bf(g1-bf2f(hv[1])); \
          hv[2]=f2bf(g2); lv[2]=f2bf(g2-bf2f(hv[2])); \
          hv[3]=f2bf(g3); lv[3]=f2bf(g3-bf2f(hv[3])); \
          int col = c4*4 + cc, scol = col ^ ((col>>3)&7); \
          unsigned idx = (bufn) + 4096u + bkh + (unsigned)scol*8u + bsub; \
          *(ushort4v*)&lds[idx] = hv; \
          *(ushort4v*)&lds[idx + 2048] = lv; \
        } \
      } \
    } while (0)

    #define COMPUTE(bufn) do { \
      short8v ah[2], al[2], bh[2], bl[2]; \
      _Pragma("unroll") \
      for (int ms = 0; ms < 2; ++ms) { \
        unsigned ai = (bufn) + (unsigned)(lhi*1024 + (wm*64 + ms*32 + l31)*8); \
        ah[ms] = *(const short8v*)&lds[ai]; \
        al[ms] = *(const short8v*)&lds[ai + 2048]; \
      } \
      _Pragma("unroll") \
      for (int ns = 0; ns < 2; ++ns) { \
        int col = wn*64 + ns*32 + l31, scol = col ^ ((col>>3)&7); \
        unsigned bi = (bufn) + 4096u + (unsigned)(lhi*1024 + scol*8); \
        bh[ns] = *(const short8v*)&lds[bi]; \
        bl[ns] = *(const short8v*)&lds[bi + 2048]; \
      } \
      __builtin_amdgcn_s_setprio(1); \
      _Pragma("unroll") \
      for (int ms = 0; ms < 2; ++ms) \
        _Pragma("unroll") \
        for (int ns = 0; ns < 2; ++ns) { \
          acc[ms][ns] = __builtin_amdgcn_mfma_f32_32x32x16_bf16(ah[ms], bh[ns], acc[ms][ns], 0, 0, 0); \
          acc[ms][ns] = __builtin_amdgcn_mfma_f32_32x32x16_bf16(ah[ms], bl[ns], acc[ms][ns], 0, 0, 0); \
          acc[ms][ns] = __builtin_amdgcn_mfma_f32_32x32x16_bf16(al[ms], bh[ns], acc[ms][ns], 0, 0, 0); \
        } \
      __builtin_amdgcn_s_setprio(0); \
    } while (0)

    f32x4v b0, b1, b2, b3;
    // prologue: stage half 0 into buffer 0
    STAGE_A(0u);
    LOAD_B();
    WRITE_B(0u);
    __syncthreads();                 // drains glds (vmcnt0) + ds_writes
    unsigned cur = 0;
    for (int h = 0; h < H; ++h) {
      const bool last = (h == H - 1);
      if (!last) {
        STAGE_A(cur ^ 8192u);        // glds A(h+1), in flight across COMPUTE
        LOAD_B();                    // B(h+1) into regs, latency hidden by COMPUTE
      }
      COMPUTE(cur);
      if (!last) WRITE_B(cur ^ 8192u);   // cvt+ds_write after compute (T14 split)
      __syncthreads();
      cur ^= 8192u;
    }
    #undef STAGE_A
    #undef LOAD_B
    #undef WRITE_B
    #undef COMPUTE
  }
  // write partial tile: D layout col=lane&31, row=(r&3)+8*(r>>2)+4*(lane>>5)
  float* Pp = P + (size_t)z * (N_PROP * D_HID);
  #pragma unroll
  for (int ms = 0; ms < 2; ++ms)
    #pragma unroll
    for (int ns = 0; ns < 2; ++ns)
      #pragma unroll
      for (int r = 0; r < 16; ++r) {
        int row = bm + wm*64 + ms*32 + (r & 3) + 8*(r >> 2) + 4*lhi;
        int col = bn + wn*64 + ns*32 + l31;
        __builtin_nontemporal_store(acc[ms][ns][r], &Pp[(size_t)row * D_HID + col]);
      }
}

__global__ void reduce_kernel(const float* __restrict__ P, float* __restrict__ X, int ksplit) {
  int i = blockIdx.x*256 + threadIdx.x;    // quad index, 65536 total
  f32x4v s = {0.0f, 0.0f, 0.0f, 0.0f};
  const f32x4v* P4 = (const f32x4v*)P;
  for (int r = 0; r < ksplit; ++r) s += P4[(size_t)r*65536 + i];
  ((f32x4v*)X)[i] = s;
}

// ---------------- heads + softmax + ORDER KEY (r13 verbatim) ----------------
__global__ void heads_kernel(const float* __restrict__ X, const float* __restrict__ bfc,
                             const float* __restrict__ wcls, const float* __restrict__ bcls,
                             const float* __restrict__ wbox, const float* __restrict__ bbox,
                             float* __restrict__ scores, float* __restrict__ deltas,
                             float* __restrict__ keym) {
  const int tid = threadIdx.x, m = blockIdx.x;
  __shared__ float xs[1024];
  __shared__ float lg[81];
  __shared__ float red[2];
  #pragma unroll
  for (int r = 0; r < 4; ++r) {
    int k = r*256 + tid;
    xs[k] = X[m*1024 + k] + bfc[k];
  }
  __syncthreads();
  for (int j = tid; j < 401; j += 256) {
    if (j < 81) {
      const float* w = wcls + j;
      float accv = bcls[j];
      #pragma unroll 8
      for (int k = 0; k < 1024; ++k) accv = fmaf(xs[k], w[(size_t)k*81], accv);
      lg[j] = accv;
    } else {
      int jb = j - 81;
      const float* w = wbox + jb;
      float accv = bbox[jb];
      #pragma unroll 8
      for (int k = 0; k < 1024; ++k) accv = fmaf(xs[k], w[(size_t)k*320], accv);
      deltas[m*320 + jb] = accv;
    }
  }
  __syncthreads();
  if (tid == 0) {
    float mx = lg[0]; int amax = 0;
    for (int j = 1; j < 81; ++j) if (lg[j] > mx) { mx = lg[j]; amax = j; }
    float sm = 0.0f;
    for (int j = 0; j < 81; ++j) sm += expf(lg[j]-mx);
    float m2 = -1e30f;
    for (int j = 0; j < 81; ++j) if (j != amax) m2 = fmaxf(m2, lg[j]);
    float s2 = 0.0f;
    for (int j = 0; j < 81; ++j) if (j != amax) s2 += expf(lg[j]-m2);
    keym[m] = (m2 - mx) + logf(s2);
    red[0] = mx; red[1] = sm;
  }
  __syncthreads();
  if (tid < 80) scores[m*80 + tid] = expf(lg[tid+1]-red[0]) / red[1];
}

// ---------------- selection + NMS + f32 output (r13 verbatim) ----------------
__global__ void detect_kernel(const float* __restrict__ scores, const float* __restrict__ deltas,
                              const float* __restrict__ props, const float* __restrict__ keym,
                              float* __restrict__ out) {
  const int tid = threadIdx.x;
  __shared__ int s_cnt;
  __shared__ float g_key[256];
  __shared__ float g_score[256];
  __shared__ int   g_idx[256];
  __shared__ float c_score[256];
  __shared__ int   c_idx[256];
  __shared__ float bxs[256][4];
  __shared__ int   bcls[256];
  __shared__ unsigned long long supp[256][4];
  if (tid == 0) s_cnt = 0;
  g_key[tid] = 1e30f; g_score[tid] = -1.0f; g_idx[tid] = 0x7FFFFFFF;
  c_score[tid] = -1.0f; c_idx[tid] = 0x7FFFFFFF;
  bxs[tid][0] = bxs[tid][1] = bxs[tid][2] = bxs[tid][3] = 0.0f;
  bcls[tid] = 0;
  __syncthreads();
  for (int t = 0; t < 80; ++t) {
    int i = t*256 + tid;
    float s = scores[i];
    if (s > 0.5f) {
      int p = atomicAdd(&s_cnt, 1);
      if (p < 256) { g_score[p] = s; g_idx[p] = i; g_key[p] = keym[i/80]; }
    }
  }
  __syncthreads();
  const int C = min(s_cnt, 256);
  if (tid < C) {
    float kt = g_key[tid]; int si = g_idx[tid]; float st = g_score[tid];
    int rank = 0;
    for (int u = 0; u < C; ++u) {
      float ku = g_key[u]; int iu = g_idx[u];
      if ((ku < kt) || (ku == kt && iu < si)) ++rank;
    }
    c_score[rank] = st; c_idx[rank] = si;
  }
  __syncthreads();
  if (tid < C) {
    int fi = c_idx[tid];
    int m = fi / 80, j = fi - m*80;
    float px1 = props[m*4+0], py1 = props[m*4+1], px2 = props[m*4+2], py2 = props[m*4+3];
    float w = px2-px1, h = py2-py1;
    float cx = px1 + 0.5f*w, cy = py1 + 0.5f*h;
    const float* d = deltas + m*320 + j*4;
    float dx = d[0]/10.0f, dy = d[1]/10.0f;
    float dw = fminf(d[2]/5.0f, SCALE_CLAMP), dh = fminf(d[3]/5.0f, SCALE_CLAMP);
    float pcx = dx*w + cx, pcy = dy*h + cy;
    float pw = expf(dw)*w, ph = expf(dh)*h;
    bxs[tid][0] = fminf(fmaxf(pcx - 0.5f*pw, 0.0f), IMG_W_F);
    bxs[tid][1] = fminf(fmaxf(pcy - 0.5f*ph, 0.0f), IMG_H_F);
    bxs[tid][2] = fminf(fmaxf(pcx + 0.5f*pw, 0.0f), IMG_W_F);
    bxs[tid][3] = fminf(fmaxf(pcy + 0.5f*ph, 0.0f), IMG_H_F);
    bcls[tid] = j;
  }
  __syncthreads();
  unsigned long long row[4] = {0,0,0,0};
  if (tid < C) {
    float ax1=bxs[tid][0], ay1=bxs[tid][1], ax2=bxs[tid][2], ay2=bxs[tid][3];
    float aarea = fmaxf(ax2-ax1,0.f)*fmaxf(ay2-ay1,0.f);
    int acl = bcls[tid];
    for (int j2 = tid+1; j2 < C; ++j2) {
      if (bcls[j2] != acl) continue;
      float b1=bxs[j2][0], b2=bxs[j2][1], b3=bxs[j2][2], b4=bxs[j2][3];
      float barea = fmaxf(b3-b1,0.f)*fmaxf(b4-b2,0.f);
      float iw = fmaxf(fminf(ax2,b3) - fmaxf(ax1,b1), 0.f);
      float ih = fmaxf(fminf(ay2,b4) - fmaxf(ay1,b2), 0.f);
      float inter = iw*ih;
      float iou = inter / fmaxf(aarea + barea - inter, 1e-9f);
      if (iou > 0.7f) row[j2>>6] |= (1ull << (j2 & 63));
    }
  }
  supp[tid][0]=row[0]; supp[tid][1]=row[1]; supp[tid][2]=row[2]; supp[tid][3]=row[3];
  __syncthreads();
  for (int i = tid; i < 1200; i += 256) out[i] = (i >= 1000) ? -1.0f : 0.0f;
  __syncthreads();
  if (tid == 0) {
    unsigned long long rem[4] = {0,0,0,0};
    int oc = 0;
    for (int i = 0; i < C; ++i) {
      if ((rem[i>>6] >> (i & 63)) & 1ull) continue;
      if (oc < 200) {
        out[oc*4+0]=bxs[i][0]; out[oc*4+1]=bxs[i][1]; out[oc*4+2]=bxs[i][2]; out[oc*4+3]=bxs[i][3];
        out[800+oc]  = c_score[i];
        out[1000+oc] = (float)bcls[i];
      }
      ++oc;
      rem[0]|=supp[i][0]; rem[1]|=supp[i][1]; rem[2]|=supp[i][2]; rem[3]|=supp[i][3];
    }
  }
}

extern "C" void kernel_launch(void* const* d_in, const int* in_sizes, int n_in,
                              void* d_out, int out_size, void* d_ws, size_t ws_size,
                              hipStream_t stream) {
  const float* F     = (const float*)d_in[0];
  const float* props = (const float*)d_in[1];
  const float* wfc   = (const float*)d_in[2];
  const float* bfc   = (const float*)d_in[3];
  const float* wcls  = (const float*)d_in[4];
  const float* bcls  = (const float*)d_in[5];
  const float* wbox  = (const float*)d_in[6];
  const float* bbox  = (const float*)d_in[7];
  float* out = (float*)d_out;
  char* wsb  = (char*)d_ws;

  const size_t abytes = (size_t)N_PROP * K_DIM * 2;      // per bf16 plane
  ushort_t* Ahi = (ushort_t*)wsb;
  ushort_t* Alo = (ushort_t*)(wsb + abytes);
  float* X  = (float*)(wsb + 2*abytes);                   // 262144
  float* SC = X + 262144;                                 // 20480
  float* DL = SC + 20480;                                 // 81920
  float* KM = DL + 81920;                                 // 256
  float* P  = KM + 256;                                   // ksplit * 1 MB (floats)
  const size_t fixed = 2*abytes + (size_t)(262144 + 20480 + 81920 + 256) * 4;
  if (ws_size < fixed + 2u*1048576u) {
    (void)hipMemsetAsync(d_out, 0x7F, (size_t)out_size*sizeof(float), stream);
    return;
  }
  int ksplit = (int)((ws_size - fixed) / ((size_t)N_PROP * D_HID * 4));
  if (ksplit > 64) ksplit = 64;
  if (ksplit >= 8) ksplit &= ~7;            // multiple of 8 -> bijective XCD swizzle
  const int steps_per = (6272 + ksplit - 1) / ksplit;
  const int nwg = 16 * ksplit;              // 16 mn-tiles (2 bm x 8 bn) per z

  roi_kernel   <<<dim3(8, N_PROP),    256, 0, stream>>>(F, props, Ahi, Alo);
  mfma_gemm    <<<nwg,                256, 0, stream>>>(Ahi, Alo, wfc, P, steps_per, nwg);
  reduce_kernel<<<256,                256, 0, stream>>>(P, X, ksplit);
  heads_kernel <<<N_PROP,             256, 0, stream>>>(X, bfc, wcls, bcls, wbox, bbox, SC, DL, KM);
  detect_kernel<<<1,                  256, 0, stream>>>(SC, DL, props, KM, out);
}

// Round 19
// 839.042 us; speedup vs baseline: 1.4199x; 1.4199x over previous
//
#include <hip/hip_runtime.h>
#include <math.h>

#define N_PROP 256
#define NUM_CLASS 80
#define H_FEAT 50
#define W_FEAT 80
#define K_DIM 200704        // 1024*14*14
#define D_HID 1024
#define SPATIAL_SCALE 0.0625f
#define SCALE_CLAMP 4.135166556742356f   // log(1000/16)
#define IMG_W_F 1280.0f
#define IMG_H_F 800.0f

typedef unsigned short ushort_t;
typedef __attribute__((ext_vector_type(8))) short short8v;       // 8 bf16 = 4 VGPR
typedef __attribute__((ext_vector_type(16))) float f32x16;       // 32x32 acc
typedef __attribute__((ext_vector_type(4))) float f32x4v;        // ext-vector float4
typedef __attribute__((ext_vector_type(2))) unsigned short ushort2v;

__device__ __forceinline__ unsigned short f2bf(float f) {
  unsigned int u = __builtin_bit_cast(unsigned int, f);
  u += 0x7FFFu + ((u >> 16) & 1u);                 // RNE
  return (unsigned short)(u >> 16);
}
__device__ __forceinline__ float bf2f(unsigned short h) {
  unsigned int u = ((unsigned int)h) << 16;
  return __builtin_bit_cast(float, u);
}

// ---------------- RoIAlign -> A as bf16 hi/lo planes (r13 verbatim) ----------------
__global__ void roi_kernel(const float* __restrict__ F, const float* __restrict__ props,
                           ushort_t* __restrict__ Ahi, ushort_t* __restrict__ Alo) {
  const int tid = threadIdx.x;
  const int m = blockIdx.y;
  const int cg = blockIdx.x;                 // channel group of 128
  __shared__ float w00[196], w01[196], w10[196], w11[196];
  __shared__ int o00[196], o01[196], o10[196], o11[196];
  const float x1s = props[m*4+0]*SPATIAL_SCALE;
  const float y1s = props[m*4+1]*SPATIAL_SCALE;
  const float x2s = props[m*4+2]*SPATIAL_SCALE;
  const float y2s = props[m*4+3]*SPATIAL_SCALE;
  const float bwf = fmaxf(x2s-x1s, 1.0f) / 14.0f;
  const float bhf = fmaxf(y2s-y1s, 1.0f) / 14.0f;
  if (tid < 196) {
    int ph = tid / 14, pw = tid - ph*14;
    float X = x1s + (pw + 0.5f)*bwf;
    float Y = y1s + (ph + 0.5f)*bhf;
    bool valid = (Y >= -1.0f) && (Y <= (float)H_FEAT) && (X >= -1.0f) && (X <= (float)W_FEAT);
    float x = fminf(fmaxf(X, 0.0f), (float)(W_FEAT-1));
    float y = fminf(fmaxf(Y, 0.0f), (float)(H_FEAT-1));
    float xf = floorf(x), yf = floorf(y);
    int ix0 = (int)xf, iy0 = (int)yf;
    int ix1 = min(ix0+1, W_FEAT-1), iy1 = min(iy0+1, H_FEAT-1);
    float lx = x-xf, ly = y-yf, hx = 1.0f-lx, hy = 1.0f-ly;
    float v = valid ? 1.0f : 0.0f;
    w00[tid] = hy*hx*v; w01[tid] = hy*lx*v; w10[tid] = ly*hx*v; w11[tid] = ly*lx*v;
    o00[tid] = iy0*W_FEAT+ix0; o01[tid] = iy0*W_FEAT+ix1;
    o10[tid] = iy1*W_FEAT+ix0; o11[tid] = iy1*W_FEAT+ix1;
  }
  __syncthreads();
  const int base_c = cg*128;
  const size_t rowbase = (size_t)m*K_DIM + (size_t)base_c*196;
  for (int it = 0; it < 49; ++it) {          // 128*196/(256*2)
    int i2 = it*512 + tid*2;                 // even; pair never crosses channel (196 even)
    int c = i2 / 196;
    int b = i2 - c*196;
    const float* f = F + (size_t)(base_c + c)*4000;
    float v0 = w00[b]*f[o00[b]] + w01[b]*f[o01[b]] + w10[b]*f[o10[b]] + w11[b]*f[o11[b]];
    float v1 = w00[b+1]*f[o00[b+1]] + w01[b+1]*f[o01[b+1]] + w10[b+1]*f[o10[b+1]] + w11[b+1]*f[o11[b+1]];
    unsigned short h0 = f2bf(v0), h1 = f2bf(v1);
    ushort2v hv; hv[0] = h0; hv[1] = h1;
    ushort2v lv; lv[0] = f2bf(v0 - bf2f(h0)); lv[1] = f2bf(v1 - bf2f(h1));
    *(ushort2v*)&Ahi[rowbase + i2] = hv;
    *(ushort2v*)&Alo[rowbase + i2] = lv;
  }
}

// ------- split-bf16 MFMA GEMM, 256x256 tile, depth-3 all-glds pipeline -------
// 512 threads = 8 waves (2M x 4N). 4 buffers x (A 16KB bf16-hi/lo + B 16KB f32) = 128KB.
// Per half-step (BK=16): wait vmcnt(8) [h ready, h+1/h+2 fly] -> barrier -> issue glds(h+3)
// -> compute h. B converted f32->bf16 hi/lo in registers at COMPUTE time.
// A buf layout (bytes): plane(2)*8192 + khalf(2)*4096 + row(256)*16   (glds linear s*16)
// B buf layout (bytes): k(16)*1024 + col(256)*4                       (glds linear s*16)
__global__ __launch_bounds__(512, 2) void mfma_gemm(
    const ushort_t* __restrict__ Ahi, const ushort_t* __restrict__ Alo,
    const float* __restrict__ B, float* __restrict__ P, int steps_per, int nwg) {
  __shared__ __align__(16) unsigned char smem[131072];
  const int tid = threadIdx.x;
  const int wv = tid >> 6, lane = tid & 63, l31 = lane & 31, lhi = lane >> 5;
  const int wm = wv >> 2, wn = wv & 3;       // 2M x 4N wave grid
  int id = blockIdx.x;
  int nid = ((nwg & 7) == 0) ? ((id & 7) * (nwg >> 3) + (id >> 3)) : id;
  const int bn = (nid & 3) * 256;
  const int z  = nid >> 2;
  const int step0 = z * steps_per;           // 32-k steps
  int steps = steps_per;
  if (step0 + steps > 6272) steps = 6272 - step0;   // may be <= 0

  f32x16 acc[4][2];
  #pragma unroll
  for (int a = 0; a < 4; ++a)
    #pragma unroll
    for (int b = 0; b < 2; ++b)
      #pragma unroll
      for (int e = 0; e < 16; ++e) acc[a][b][e] = 0.0f;

  if (steps > 0) {
    const int H = steps * 2;                 // 16-k halves
    // A glds sources: s = i*512 + tid: plane=s>>9, khalf=(s>>8)&1, row=s&255
    const ushort_t* asrc[2];
    #pragma unroll
    for (int i = 0; i < 2; ++i) {
      int s = i*512 + tid;
      int plane = s >> 9, kb = (s >> 8) & 1, row = s & 255;
      const ushort_t* basep = plane ? Alo : Ahi;
      asrc[i] = basep + (size_t)row * K_DIM + step0*32 + kb*8;
    }
    // B glds sources: s = i*512 + tid: krow=s>>6 (wave-uniform), col4=s&63
    const float* bsrc[2];
    #pragma unroll
    for (int i = 0; i < 2; ++i) {
      int s = i*512 + tid;
      int krow = s >> 6, col4 = s & 63;
      bsrc[i] = B + (size_t)(step0*32 + krow) * D_HID + bn + col4*4;
    }

    #define ISSUE(h) do { \
      unsigned ab_ = (unsigned)((h) & 3) * 16384u; \
      unsigned bb_ = 65536u + (unsigned)((h) & 3) * 16384u; \
      _Pragma("unroll") \
      for (int i = 0; i < 2; ++i) { \
        __builtin_amdgcn_global_load_lds(asrc[i], &smem[ab_ + (unsigned)(i*512 + tid)*16u], 16, 0, 0); \
        asrc[i] += 16; } \
      _Pragma("unroll") \
      for (int i = 0; i < 2; ++i) { \
        __builtin_amdgcn_global_load_lds(bsrc[i], &smem[bb_ + (unsigned)(i*512 + tid)*16u], 16, 0, 0); \
        bsrc[i] += 16 * D_HID; } \
    } while (0)

    #define COMPUTE(h) do { \
      unsigned ab_ = (unsigned)((h) & 3) * 16384u; \
      unsigned bb_ = 65536u + (unsigned)((h) & 3) * 16384u; \
      short8v ah[4], al[4], bh[2], bl[2]; \
      _Pragma("unroll") \
      for (int ms = 0; ms < 4; ++ms) { \
        unsigned abyte = ab_ + (unsigned)(lhi*4096 + (wm*128 + ms*32 + l31)*16); \
        ah[ms] = *(const short8v*)&smem[abyte]; \
        al[ms] = *(const short8v*)&smem[abyte + 8192u]; \
      } \
      _Pragma("unroll") \
      for (int ns = 0; ns < 2; ++ns) { \
        int col = wn*64 + ns*32 + l31; \
        unsigned bbyte = bb_ + (unsigned)lhi*8192u + (unsigned)col*4u; \
        _Pragma("unroll") \
        for (int j = 0; j < 8; ++j) { \
          float g = *(const float*)&smem[bbyte + (unsigned)j*1024u]; \
          unsigned short h16 = f2bf(g); \
          bh[ns][j] = (short)h16; \
          bl[ns][j] = (short)f2bf(g - bf2f(h16)); \
        } \
      } \
      __builtin_amdgcn_s_setprio(1); \
      _Pragma("unroll") \
      for (int ms = 0; ms < 4; ++ms) \
        _Pragma("unroll") \
        for (int ns = 0; ns < 2; ++ns) { \
          acc[ms][ns] = __builtin_amdgcn_mfma_f32_32x32x16_bf16(ah[ms], bh[ns], acc[ms][ns], 0, 0, 0); \
          acc[ms][ns] = __builtin_amdgcn_mfma_f32_32x32x16_bf16(ah[ms], bl[ns], acc[ms][ns], 0, 0, 0); \
          acc[ms][ns] = __builtin_amdgcn_mfma_f32_32x32x16_bf16(al[ms], bh[ns], acc[ms][ns], 0, 0, 0); \
        } \
      __builtin_amdgcn_s_setprio(0); \
    } while (0)

    // prologue: fill pipeline 3 deep
    const int pre = (H < 3) ? H : 3;
    for (int hp = 0; hp < pre; ++hp) ISSUE(hp);
    for (int h = 0; h < H; ++h) {
      const int rem = H - 1 - h;
      if (rem >= 2)      asm volatile("s_waitcnt vmcnt(8)" ::: "memory");
      else if (rem == 1) asm volatile("s_waitcnt vmcnt(4)" ::: "memory");
      else               asm volatile("s_waitcnt vmcnt(0)" ::: "memory");
      __builtin_amdgcn_sched_barrier(0);
      __builtin_amdgcn_s_barrier();
      __builtin_amdgcn_sched_barrier(0);
      if (h + 3 < H) ISSUE(h + 3);     // overwrites buf (h-1)&3 -- all readers passed barrier
      COMPUTE(h);
    }
    #undef ISSUE
    #undef COMPUTE
  }
  // write partial tile: D layout col=lane&31, row=(r&3)+8*(r>>2)+4*(lane>>5)
  float* Pp = P + (size_t)z * (N_PROP * D_HID);
  #pragma unroll
  for (int ms = 0; ms < 4; ++ms)
    #pragma unroll
    for (int ns = 0; ns < 2; ++ns)
      #pragma unroll
      for (int r = 0; r < 16; ++r) {
        int row = wm*128 + ms*32 + (r & 3) + 8*(r >> 2) + 4*lhi;
        int col = bn + wn*64 + ns*32 + l31;
        __builtin_nontemporal_store(acc[ms][ns][r], &Pp[(size_t)row * D_HID + col]);
      }
}

__global__ void reduce_kernel(const float* __restrict__ P, float* __restrict__ X, int ksplit) {
  int i = blockIdx.x*256 + threadIdx.x;    // quad index, 65536 total
  f32x4v s = {0.0f, 0.0f, 0.0f, 0.0f};
  const f32x4v* P4 = (const f32x4v*)P;
  for (int r = 0; r < ksplit; ++r) s += P4[(size_t)r*65536 + i];
  ((f32x4v*)X)[i] = s;
}

// ---------------- heads + softmax + ORDER KEY (r13 verbatim) ----------------
__global__ void heads_kernel(const float* __restrict__ X, const float* __restrict__ bfc,
                             const float* __restrict__ wcls, const float* __restrict__ bcls,
                             const float* __restrict__ wbox, const float* __restrict__ bbox,
                             float* __restrict__ scores, float* __restrict__ deltas,
                             float* __restrict__ keym) {
  const int tid = threadIdx.x, m = blockIdx.x;
  __shared__ float xs[1024];
  __shared__ float lg[81];
  __shared__ float red[2];
  #pragma unroll
  for (int r = 0; r < 4; ++r) {
    int k = r*256 + tid;
    xs[k] = X[m*1024 + k] + bfc[k];
  }
  __syncthreads();
  for (int j = tid; j < 401; j += 256) {
    if (j < 81) {
      const float* w = wcls + j;
      float accv = bcls[j];
      #pragma unroll 8
      for (int k = 0; k < 1024; ++k) accv = fmaf(xs[k], w[(size_t)k*81], accv);
      lg[j] = accv;
    } else {
      int jb = j - 81;
      const float* w = wbox + jb;
      float accv = bbox[jb];
      #pragma unroll 8
      for (int k = 0; k < 1024; ++k) accv = fmaf(xs[k], w[(size_t)k*320], accv);
      deltas[m*320 + jb] = accv;
    }
  }
  __syncthreads();
  if (tid == 0) {
    float mx = lg[0]; int amax = 0;
    for (int j = 1; j < 81; ++j) if (lg[j] > mx) { mx = lg[j]; amax = j; }
    float sm = 0.0f;
    for (int j = 0; j < 81; ++j) sm += expf(lg[j]-mx);
    float m2 = -1e30f;
    for (int j = 0; j < 81; ++j) if (j != amax) m2 = fmaxf(m2, lg[j]);
    float s2 = 0.0f;
    for (int j = 0; j < 81; ++j) if (j != amax) s2 += expf(lg[j]-m2);
    keym[m] = (m2 - mx) + logf(s2);
    red[0] = mx; red[1] = sm;
  }
  __syncthreads();
  if (tid < 80) scores[m*80 + tid] = expf(lg[tid+1]-red[0]) / red[1];
}

// ---------------- selection + NMS + f32 output (r13 verbatim) ----------------
__global__ void detect_kernel(const float* __restrict__ scores, const float* __restrict__ deltas,
                              const float* __restrict__ props, const float* __restrict__ keym,
                              float* __restrict__ out) {
  const int tid = threadIdx.x;
  __shared__ int s_cnt;
  __shared__ float g_key[256];
  __shared__ float g_score[256];
  __shared__ int   g_idx[256];
  __shared__ float c_score[256];
  __shared__ int   c_idx[256];
  __shared__ float bxs[256][4];
  __shared__ int   bcls[256];
  __shared__ unsigned long long supp[256][4];
  if (tid == 0) s_cnt = 0;
  g_key[tid] = 1e30f; g_score[tid] = -1.0f; g_idx[tid] = 0x7FFFFFFF;
  c_score[tid] = -1.0f; c_idx[tid] = 0x7FFFFFFF;
  bxs[tid][0] = bxs[tid][1] = bxs[tid][2] = bxs[tid][3] = 0.0f;
  bcls[tid] = 0;
  __syncthreads();
  for (int t = 0; t < 80; ++t) {
    int i = t*256 + tid;
    float s = scores[i];
    if (s > 0.5f) {
      int p = atomicAdd(&s_cnt, 1);
      if (p < 256) { g_score[p] = s; g_idx[p] = i; g_key[p] = keym[i/80]; }
    }
  }
  __syncthreads();
  const int C = min(s_cnt, 256);
  if (tid < C) {
    float kt = g_key[tid]; int si = g_idx[tid]; float st = g_score[tid];
    int rank = 0;
    for (int u = 0; u < C; ++u) {
      float ku = g_key[u]; int iu = g_idx[u];
      if ((ku < kt) || (ku == kt && iu < si)) ++rank;
    }
    c_score[rank] = st; c_idx[rank] = si;
  }
  __syncthreads();
  if (tid < C) {
    int fi = c_idx[tid];
    int m = fi / 80, j = fi - m*80;
    float px1 = props[m*4+0], py1 = props[m*4+1], px2 = props[m*4+2], py2 = props[m*4+3];
    float w = px2-px1, h = py2-py1;
    float cx = px1 + 0.5f*w, cy = py1 + 0.5f*h;
    const float* d = deltas + m*320 + j*4;
    float dx = d[0]/10.0f, dy = d[1]/10.0f;
    float dw = fminf(d[2]/5.0f, SCALE_CLAMP), dh = fminf(d[3]/5.0f, SCALE_CLAMP);
    float pcx = dx*w + cx, pcy = dy*h + cy;
    float pw = expf(dw)*w, ph = expf(dh)*h;
    bxs[tid][0] = fminf(fmaxf(pcx - 0.5f*pw, 0.0f), IMG_W_F);
    bxs[tid][1] = fminf(fmaxf(pcy - 0.5f*ph, 0.0f), IMG_H_F);
    bxs[tid][2] = fminf(fmaxf(pcx + 0.5f*pw, 0.0f), IMG_W_F);
    bxs[tid][3] = fminf(fmaxf(pcy + 0.5f*ph, 0.0f), IMG_H_F);
    bcls[tid] = j;
  }
  __syncthreads();
  unsigned long long row[4] = {0,0,0,0};
  if (tid < C) {
    float ax1=bxs[tid][0], ay1=bxs[tid][1], ax2=bxs[tid][2], ay2=bxs[tid][3];
    float aarea = fmaxf(ax2-ax1,0.f)*fmaxf(ay2-ay1,0.f);
    int acl = bcls[tid];
    for (int j2 = tid+1; j2 < C; ++j2) {
      if (bcls[j2] != acl) continue;
      float b1=bxs[j2][0], b2=bxs[j2][1], b3=bxs[j2][2], b4=bxs[j2][3];
      float barea = fmaxf(b3-b1,0.f)*fmaxf(b4-b2,0.f);
      float iw = fmaxf(fminf(ax2,b3) - fmaxf(ax1,b1), 0.f);
      float ih = fmaxf(fminf(ay2,b4) - fmaxf(ay1,b2), 0.f);
      float inter = iw*ih;
      float iou = inter / fmaxf(aarea + barea - inter, 1e-9f);
      if (iou > 0.7f) row[j2>>6] |= (1ull << (j2 & 63));
    }
  }
  supp[tid][0]=row[0]; supp[tid][1]=row[1]; supp[tid][2]=row[2]; supp[tid][3]=row[3];
  __syncthreads();
  for (int i = tid; i < 1200; i += 256) out[i] = (i >= 1000) ? -1.0f : 0.0f;
  __syncthreads();
  if (tid == 0) {
    unsigned long long rem[4] = {0,0,0,0};
    int oc = 0;
    for (int i = 0; i < C; ++i) {
      if ((rem[i>>6] >> (i & 63)) & 1ull) continue;
      if (oc < 200) {
        out[oc*4+0]=bxs[i][0]; out[oc*4+1]=bxs[i][1]; out[oc*4+2]=bxs[i][2]; out[oc*4+3]=bxs[i][3];
        out[800+oc]  = c_score[i];
        out[1000+oc] = (float)bcls[i];
      }
      ++oc;
      rem[0]|=supp[i][0]; rem[1]|=supp[i][1]; rem[2]|=supp[i][2]; rem[3]|=supp[i][3];
    }
  }
}

extern "C" void kernel_launch(void* const* d_in, const int* in_sizes, int n_in,
                              void* d_out, int out_size, void* d_ws, size_t ws_size,
                              hipStream_t stream) {
  const float* F     = (const float*)d_in[0];
  const float* props = (const float*)d_in[1];
  const float* wfc   = (const float*)d_in[2];
  const float* bfc   = (const float*)d_in[3];
  const float* wcls  = (const float*)d_in[4];
  const float* bcls  = (const float*)d_in[5];
  const float* wbox  = (const float*)d_in[6];
  const float* bbox  = (const float*)d_in[7];
  float* out = (float*)d_out;
  char* wsb  = (char*)d_ws;

  const size_t abytes = (size_t)N_PROP * K_DIM * 2;      // per bf16 plane
  ushort_t* Ahi = (ushort_t*)wsb;
  ushort_t* Alo = (ushort_t*)(wsb + abytes);
  float* X  = (float*)(wsb + 2*abytes);                   // 262144
  float* SC = X + 262144;                                 // 20480
  float* DL = SC + 20480;                                 // 81920
  float* KM = DL + 81920;                                 // 256
  float* P  = KM + 256;                                   // ksplit * 1 MB (floats)
  const size_t fixed = 2*abytes + (size_t)(262144 + 20480 + 81920 + 256) * 4;
  if (ws_size < fixed + 2u*1048576u) {
    (void)hipMemsetAsync(d_out, 0x7F, (size_t)out_size*sizeof(float), stream);
    return;
  }
  int ksplit = (int)((ws_size - fixed) / ((size_t)N_PROP * D_HID * 4));
  if (ksplit > 64) ksplit = 64;
  if (ksplit >= 8) ksplit &= ~7;            // multiple of 8 -> bijective XCD swizzle
  const int steps_per = (6272 + ksplit - 1) / ksplit;
  const int nwg = 4 * ksplit;

  roi_kernel   <<<dim3(8, N_PROP),    256, 0, stream>>>(F, props, Ahi, Alo);
  mfma_gemm    <<<nwg,                512, 0, stream>>>(Ahi, Alo, wfc, P, steps_per, nwg);
  reduce_kernel<<<256,                256, 0, stream>>>(P, X, ksplit);
  heads_kernel <<<N_PROP,             256, 0, stream>>>(X, bfc, wcls, bcls, wbox, bbox, SC, DL, KM);
  detect_kernel<<<1,                  256, 0, stream>>>(SC, DL, props, KM, out);
}

// Round 20
// 797.747 us; speedup vs baseline: 1.4935x; 1.0518x over previous
//
#include <hip/hip_runtime.h>
#include <math.h>

#define N_PROP 256
#define NUM_CLASS 80
#define H_FEAT 50
#define W_FEAT 80
#define K_DIM 200704        // 1024*14*14
#define D_HID 1024
#define SPATIAL_SCALE 0.0625f
#define SCALE_CLAMP 4.135166556742356f   // log(1000/16)
#define IMG_W_F 1280.0f
#define IMG_H_F 800.0f

typedef unsigned short ushort_t;
typedef __attribute__((ext_vector_type(8))) short short8v;       // 8 bf16 = 4 VGPR
typedef __attribute__((ext_vector_type(16))) float f32x16;       // 32x32 acc
typedef __attribute__((ext_vector_type(4))) float f32x4v;        // ext-vector float4
typedef __attribute__((ext_vector_type(4))) unsigned short ushort4v;
typedef __attribute__((ext_vector_type(2))) unsigned short ushort2v;

__device__ __forceinline__ unsigned short f2bf(float f) {
  unsigned int u = __builtin_bit_cast(unsigned int, f);
  u += 0x7FFFu + ((u >> 16) & 1u);                 // RNE
  return (unsigned short)(u >> 16);
}
__device__ __forceinline__ float bf2f(unsigned short h) {
  unsigned int u = ((unsigned int)h) << 16;
  return __builtin_bit_cast(float, u);
}

// ---------------- RoIAlign -> A as bf16 hi/lo planes, k = c*196 + ph*14 + pw ----------------
__global__ void roi_kernel(const float* __restrict__ F, const float* __restrict__ props,
                           ushort_t* __restrict__ Ahi, ushort_t* __restrict__ Alo) {
  const int tid = threadIdx.x;
  const int m = blockIdx.y;
  const int cg = blockIdx.x;                 // channel group of 128
  __shared__ float w00[196], w01[196], w10[196], w11[196];
  __shared__ int o00[196], o01[196], o10[196], o11[196];
  const float x1s = props[m*4+0]*SPATIAL_SCALE;
  const float y1s = props[m*4+1]*SPATIAL_SCALE;
  const float x2s = props[m*4+2]*SPATIAL_SCALE;
  const float y2s = props[m*4+3]*SPATIAL_SCALE;
  const float bwf = fmaxf(x2s-x1s, 1.0f) / 14.0f;
  const float bhf = fmaxf(y2s-y1s, 1.0f) / 14.0f;
  if (tid < 196) {
    int ph = tid / 14, pw = tid - ph*14;
    float X = x1s + (pw + 0.5f)*bwf;
    float Y = y1s + (ph + 0.5f)*bhf;
    bool valid = (Y >= -1.0f) && (Y <= (float)H_FEAT) && (X >= -1.0f) && (X <= (float)W_FEAT);
    float x = fminf(fmaxf(X, 0.0f), (float)(W_FEAT-1));
    float y = fminf(fmaxf(Y, 0.0f), (float)(H_FEAT-1));
    float xf = floorf(x), yf = floorf(y);
    int ix0 = (int)xf, iy0 = (int)yf;
    int ix1 = min(ix0+1, W_FEAT-1), iy1 = min(iy0+1, H_FEAT-1);
    float lx = x-xf, ly = y-yf, hx = 1.0f-lx, hy = 1.0f-ly;
    float v = valid ? 1.0f : 0.0f;
    w00[tid] = hy*hx*v; w01[tid] = hy*lx*v; w10[tid] = ly*hx*v; w11[tid] = ly*lx*v;
    o00[tid] = iy0*W_FEAT+ix0; o01[tid] = iy0*W_FEAT+ix1;
    o10[tid] = iy1*W_FEAT+ix0; o11[tid] = iy1*W_FEAT+ix1;
  }
  __syncthreads();
  const int base_c = cg*128;
  const size_t rowbase = (size_t)m*K_DIM + (size_t)base_c*196;
  for (int it = 0; it < 49; ++it) {          // 128*196/(256*2)
    int i2 = it*512 + tid*2;                 // even; pair never crosses channel (196 even)
    int c = i2 / 196;
    int b = i2 - c*196;
    const float* f = F + (size_t)(base_c + c)*4000;
    float v0 = w00[b]*f[o00[b]] + w01[b]*f[o01[b]] + w10[b]*f[o10[b]] + w11[b]*f[o11[b]];
    float v1 = w00[b+1]*f[o00[b+1]] + w01[b+1]*f[o01[b+1]] + w10[b+1]*f[o10[b+1]] + w11[b+1]*f[o11[b+1]];
    unsigned short h0 = f2bf(v0), h1 = f2bf(v1);
    ushort2v hv; hv[0] = h0; hv[1] = h1;
    ushort2v lv; lv[0] = f2bf(v0 - bf2f(h0)); lv[1] = f2bf(v1 - bf2f(h1));
    *(ushort2v*)&Ahi[rowbase + i2] = hv;
    *(ushort2v*)&Alo[rowbase + i2] = lv;
  }
}

// ------- split-bf16 MFMA GEMM, 256x256 tile, counted-vmcnt pipeline (T3+T4+T5) -------
// 512 threads = 8 waves (2M x 4N). BK=16 halves. A: 3 buffers (depth-2 glds prefetch),
// B: 2 buffers (reg-staged, cvt, swizzled ds_write). Never vmcnt(0) in steady state.
// Per A buffer (8192 ushorts): plane(2)*4096 + kb(2)*2048 + row(256)*8  (glds linear s*8)
// Per B buffer (8192 ushorts): plane(2)*4096 + kbh(2)*2048 + scol(256)*8 + sub, scol=col^((col>>3)&7)
__global__ __launch_bounds__(512, 2) void mfma_gemm(
    const ushort_t* __restrict__ Ahi, const ushort_t* __restrict__ Alo,
    const float* __restrict__ B, float* __restrict__ P, int steps_per, int nwg) {
  __shared__ ushort_t lds[40960];            // 80 KB: A 3x16KB @0, B 2x16KB @24576
  const int tid = threadIdx.x;
  const int wv = tid >> 6, lane = tid & 63, l31 = lane & 31, lhi = lane >> 5;
  const int wm = wv >> 2, wn = wv & 3;       // 2M x 4N wave grid
  int id = blockIdx.x;
  int nid = ((nwg & 7) == 0) ? ((id & 7) * (nwg >> 3) + (id >> 3)) : id;
  const int bn = (nid & 3) * 256;
  const int z  = nid >> 2;
  const int step0 = z * steps_per;           // 32-k steps
  int steps = steps_per;
  if (step0 + steps > 6272) steps = 6272 - step0;   // may be <= 0

  f32x16 acc[4][2];
  #pragma unroll
  for (int a = 0; a < 4; ++a)
    #pragma unroll
    for (int b = 0; b < 2; ++b)
      #pragma unroll
      for (int e = 0; e < 16; ++e) acc[a][b][e] = 0.0f;

  if (steps > 0) {
    const int H = steps * 2;                 // 16-k halves
    const ushort_t* asrc[2];
    #pragma unroll
    for (int i = 0; i < 2; ++i) {
      int s = i*512 + tid;
      int plane = s >> 9, kb = (s >> 8) & 1, row = s & 255;
      const ushort_t* basep = plane ? Alo : Ahi;
      asrc[i] = basep + (size_t)row * K_DIM + step0*32 + kb*8;
    }
    const int p = tid >> 6, c4 = tid & 63;
    const bool bstage = (tid < 256);
    const float* bsrc = B + (size_t)(step0*32 + 4*p) * D_HID + bn + c4*4;
    const unsigned bkbh = (unsigned)(p >> 1) * 2048u, bsub = (unsigned)((p & 1) * 4);

    #define STAGE_A(aoff) do { \
      _Pragma("unroll") \
      for (int i = 0; i < 2; ++i) { \
        __builtin_amdgcn_global_load_lds(asrc[i], &lds[(aoff) + (unsigned)(i*512 + tid)*8u], 16, 0, 0); \
        asrc[i] += 16; } \
    } while (0)

    #define LOAD_B() do { \
      if (bstage) { \
        b0 = __builtin_nontemporal_load((const f32x4v*)(bsrc)); \
        b1 = __builtin_nontemporal_load((const f32x4v*)(bsrc + D_HID)); \
        b2 = __builtin_nontemporal_load((const f32x4v*)(bsrc + 2*D_HID)); \
        b3 = __builtin_nontemporal_load((const f32x4v*)(bsrc + 3*D_HID)); \
      } \
      bsrc += 16 * D_HID; \
    } while (0)

    #define WRITE_B(boff) do { \
      if (bstage) { \
        _Pragma("unroll") \
        for (int cc = 0; cc < 4; ++cc) { \
          float g0 = b0[cc], g1 = b1[cc], g2 = b2[cc], g3 = b3[cc]; \
          ushort4v hv, lv; \
          hv[0]=f2bf(g0); lv[0]=f2bf(g0-bf2f(hv[0])); \
          hv[1]=f2bf(g1); lv[1]=f2bf(g1-bf2f(hv[1])); \
          hv[2]=f2bf(g2); lv[2]=f2bf(g2-bf2f(hv[2])); \
          hv[3]=f2bf(g3); lv[3]=f2bf(g3-bf2f(hv[3])); \
          int col = c4*4 + cc, scol = col ^ ((col>>3)&7); \
          unsigned idx = (boff) + bkbh + (unsigned)scol*8u + bsub; \
          *(ushort4v*)&lds[idx] = hv; \
          *(ushort4v*)&lds[idx + 4096] = lv; \
        } \
      } \
    } while (0)

    #define COMPUTE(aoff, boff) do { \
      short8v ah[4], al[4], bh[2], bl[2]; \
      _Pragma("unroll") \
      for (int ms = 0; ms < 4; ++ms) { \
        unsigned ai = (aoff) + (unsigned)(lhi*2048 + (wm*128 + ms*32 + l31)*8); \
        ah[ms] = *(const short8v*)&lds[ai]; \
        al[ms] = *(const short8v*)&lds[ai + 4096]; \
      } \
      _Pragma("unroll") \
      for (int ns = 0; ns < 2; ++ns) { \
        int col = wn*64 + ns*32 + l31, scol = col ^ ((col>>3)&7); \
        unsigned bi = (boff) + (unsigned)(lhi*2048 + scol*8); \
        bh[ns] = *(const short8v*)&lds[bi]; \
        bl[ns] = *(const short8v*)&lds[bi + 4096]; \
      } \
      __builtin_amdgcn_s_setprio(1); \
      _Pragma("unroll") \
      for (int ms = 0; ms < 4; ++ms) \
        _Pragma("unroll") \
        for (int ns = 0; ns < 2; ++ns) { \
          acc[ms][ns] = __builtin_amdgcn_mfma_f32_32x32x16_bf16(ah[ms], bh[ns], acc[ms][ns], 0, 0, 0); \
          acc[ms][ns] = __builtin_amdgcn_mfma_f32_32x32x16_bf16(ah[ms], bl[ns], acc[ms][ns], 0, 0, 0); \
          acc[ms][ns] = __builtin_amdgcn_mfma_f32_32x32x16_bf16(al[ms], bh[ns], acc[ms][ns], 0, 0, 0); \
        } \
      __builtin_amdgcn_s_setprio(0); \
    } while (0)

    f32x4v b0, b1, b2, b3;
    // ---- prologue: B(0) -> bufB0; A(0),A(1) glds in flight ----
    LOAD_B();                  // B(0): 4 vm
    STAGE_A(0u);               // A(0): 2 vm
    STAGE_A(8192u);            // A(1): 2 vm
    asm volatile("s_waitcnt vmcnt(4)" ::: "memory");   // B(0) done (A0,A1 fly)
    __builtin_amdgcn_sched_barrier(0);
    WRITE_B(24576u);
    asm volatile("s_waitcnt vmcnt(2)" ::: "memory");   // A(0) done (A1 flies)
    asm volatile("s_waitcnt lgkmcnt(0)" ::: "memory");
    __builtin_amdgcn_s_barrier();
    __builtin_amdgcn_sched_barrier(0);

    unsigned aC = 0u, aN = 8192u, aNN = 16384u;
    unsigned bC = 24576u, bN = 32768u;
    for (int h = 0; h < H; ++h) {
      const int rem = H - 1 - h;
      if (rem > 0) LOAD_B();            // B(h+1) -> regs (4 vm)
      if (rem > 1) STAGE_A(aNN);        // A(h+2) glds (2 vm), crosses barrier
      COMPUTE(aC, bC);
      if (rem > 1)       asm volatile("s_waitcnt vmcnt(2)" ::: "memory");  // A(h+1)+B(h+1) done
      else if (rem == 1) asm volatile("s_waitcnt vmcnt(0)" ::: "memory");
      __builtin_amdgcn_sched_barrier(0);
      if (rem > 0) WRITE_B(bN);
      asm volatile("s_waitcnt lgkmcnt(0)" ::: "memory");
      __builtin_amdgcn_s_barrier();
      __builtin_amdgcn_sched_barrier(0);
      unsigned t = aC; aC = aN; aN = aNN; aNN = t;
      t = bC; bC = bN; bN = t;
    }
    #undef STAGE_A
    #undef LOAD_B
    #undef WRITE_B
    #undef COMPUTE
  }
  // write partial tile: D layout col=lane&31, row=(r&3)+8*(r>>2)+4*(lane>>5)
  float* Pp = P + (size_t)z * (N_PROP * D_HID);
  #pragma unroll
  for (int ms = 0; ms < 4; ++ms)
    #pragma unroll
    for (int ns = 0; ns < 2; ++ns)
      #pragma unroll
      for (int r = 0; r < 16; ++r) {
        int row = wm*128 + ms*32 + (r & 3) + 8*(r >> 2) + 4*lhi;
        int col = bn + wn*64 + ns*32 + l31;
        __builtin_nontemporal_store(acc[ms][ns][r], &Pp[(size_t)row * D_HID + col]);
      }
}

__global__ void reduce_kernel(const float* __restrict__ P, float* __restrict__ X, int ksplit) {
  int i = blockIdx.x*256 + threadIdx.x;    // quad index, 65536 total
  f32x4v s = {0.0f, 0.0f, 0.0f, 0.0f};
  const f32x4v* P4 = (const f32x4v*)P;
  for (int r = 0; r < ksplit; ++r) s += P4[(size_t)r*65536 + i];
  ((f32x4v*)X)[i] = s;
}

// ---------------- heads + softmax + ORDER KEY (log-rest, saturation-proof) ----------------
__global__ void heads_kernel(const float* __restrict__ X, const float* __restrict__ bfc,
                             const float* __restrict__ wcls, const float* __restrict__ bcls,
                             const float* __restrict__ wbox, const float* __restrict__ bbox,
                             float* __restrict__ scores, float* __restrict__ deltas,
                             float* __restrict__ keym) {
  const int tid = threadIdx.x, m = blockIdx.x;
  __shared__ float xs[1024];
  __shared__ float lg[81];
  __shared__ float red[2];
  #pragma unroll
  for (int r = 0; r < 4; ++r) {
    int k = r*256 + tid;
    xs[k] = X[m*1024 + k] + bfc[k];
  }
  __syncthreads();
  for (int j = tid; j < 401; j += 256) {
    if (j < 81) {
      const float* w = wcls + j;
      float accv = bcls[j];
      #pragma unroll 8
      for (int k = 0; k < 1024; ++k) accv = fmaf(xs[k], w[(size_t)k*81], accv);
      lg[j] = accv;
    } else {
      int jb = j - 81;
      const float* w = wbox + jb;
      float accv = bbox[jb];
      #pragma unroll 8
      for (int k = 0; k < 1024; ++k) accv = fmaf(xs[k], w[(size_t)k*320], accv);
      deltas[m*320 + jb] = accv;
    }
  }
  __syncthreads();
  if (tid == 0) {
    float mx = lg[0]; int amax = 0;
    for (int j = 1; j < 81; ++j) if (lg[j] > mx) { mx = lg[j]; amax = j; }
    float sm = 0.0f;
    for (int j = 0; j < 81; ++j) sm += expf(lg[j]-mx);
    float m2 = -1e30f;
    for (int j = 0; j < 81; ++j) if (j != amax) m2 = fmaxf(m2, lg[j]);
    float s2 = 0.0f;
    for (int j = 0; j < 81; ++j) if (j != amax) s2 += expf(lg[j]-m2);
    keym[m] = (m2 - mx) + logf(s2);
    red[0] = mx; red[1] = sm;
  }
  __syncthreads();
  if (tid < 80) scores[m*80 + tid] = expf(lg[tid+1]-red[0]) / red[1];
}

// ---------------- selection + NMS + f32 output ----------------
__global__ void detect_kernel(const float* __restrict__ scores, const float* __restrict__ deltas,
                              const float* __restrict__ props, const float* __restrict__ keym,
                              float* __restrict__ out) {
  const int tid = threadIdx.x;
  __shared__ int s_cnt;
  __shared__ float g_key[256];
  __shared__ float g_score[256];
  __shared__ int   g_idx[256];
  __shared__ float c_score[256];
  __shared__ int   c_idx[256];
  __shared__ float bxs[256][4];
  __shared__ int   bcls[256];
  __shared__ unsigned long long supp[256][4];
  if (tid == 0) s_cnt = 0;
  g_key[tid] = 1e30f; g_score[tid] = -1.0f; g_idx[tid] = 0x7FFFFFFF;
  c_score[tid] = -1.0f; c_idx[tid] = 0x7FFFFFFF;
  bxs[tid][0] = bxs[tid][1] = bxs[tid][2] = bxs[tid][3] = 0.0f;
  bcls[tid] = 0;
  __syncthreads();
  for (int t = 0; t < 80; ++t) {
    int i = t*256 + tid;
    float s = scores[i];
    if (s > 0.5f) {
      int p = atomicAdd(&s_cnt, 1);
      if (p < 256) { g_score[p] = s; g_idx[p] = i; g_key[p] = keym[i/80]; }
    }
  }
  __syncthreads();
  const int C = min(s_cnt, 256);
  if (tid < C) {
    float kt = g_key[tid]; int si = g_idx[tid]; float st = g_score[tid];
    int rank = 0;
    for (int u = 0; u < C; ++u) {
      float ku = g_key[u]; int iu = g_idx[u];
      if ((ku < kt) || (ku == kt && iu < si)) ++rank;
    }
    c_score[rank] = st; c_idx[rank] = si;
  }
  __syncthreads();
  if (tid < C) {
    int fi = c_idx[tid];
    int m = fi / 80, j = fi - m*80;
    float px1 = props[m*4+0], py1 = props[m*4+1], px2 = props[m*4+2], py2 = props[m*4+3];
    float w = px2-px1, h = py2-py1;
    float cx = px1 + 0.5f*w, cy = py1 + 0.5f*h;
    const float* d = deltas + m*320 + j*4;
    float dx = d[0]/10.0f, dy = d[1]/10.0f;
    float dw = fminf(d[2]/5.0f, SCALE_CLAMP), dh = fminf(d[3]/5.0f, SCALE_CLAMP);
    float pcx = dx*w + cx, pcy = dy*h + cy;
    float pw = expf(dw)*w, ph = expf(dh)*h;
    bxs[tid][0] = fminf(fmaxf(pcx - 0.5f*pw, 0.0f), IMG_W_F);
    bxs[tid][1] = fminf(fmaxf(pcy - 0.5f*ph, 0.0f), IMG_H_F);
    bxs[tid][2] = fminf(fmaxf(pcx + 0.5f*pw, 0.0f), IMG_W_F);
    bxs[tid][3] = fminf(fmaxf(pcy + 0.5f*ph, 0.0f), IMG_H_F);
    bcls[tid] = j;
  }
  __syncthreads();
  unsigned long long row[4] = {0,0,0,0};
  if (tid < C) {
    float ax1=bxs[tid][0], ay1=bxs[tid][1], ax2=bxs[tid][2], ay2=bxs[tid][3];
    float aarea = fmaxf(ax2-ax1,0.f)*fmaxf(ay2-ay1,0.f);
    int acl = bcls[tid];
    for (int j2 = tid+1; j2 < C; ++j2) {
      if (bcls[j2] != acl) continue;
      float b1=bxs[j2][0], b2=bxs[j2][1], b3=bxs[j2][2], b4=bxs[j2][3];
      float barea = fmaxf(b3-b1,0.f)*fmaxf(b4-b2,0.f);
      float iw = fmaxf(fminf(ax2,b3) - fmaxf(ax1,b1), 0.f);
      float ih = fmaxf(fminf(ay2,b4) - fmaxf(ay1,b2), 0.f);
      float inter = iw*ih;
      float iou = inter / fmaxf(aarea + barea - inter, 1e-9f);
      if (iou > 0.7f) row[j2>>6] |= (1ull << (j2 & 63));
    }
  }
  supp[tid][0]=row[0]; supp[tid][1]=row[1]; supp[tid][2]=row[2]; supp[tid][3]=row[3];
  __syncthreads();
  for (int i = tid; i < 1200; i += 256) out[i] = (i >= 1000) ? -1.0f : 0.0f;
  __syncthreads();
  if (tid == 0) {
    unsigned long long rem[4] = {0,0,0,0};
    int oc = 0;
    for (int i = 0; i < C; ++i) {
      if ((rem[i>>6] >> (i & 63)) & 1ull) continue;
      if (oc < 200) {
        out[oc*4+0]=bxs[i][0]; out[oc*4+1]=bxs[i][1]; out[oc*4+2]=bxs[i][2]; out[oc*4+3]=bxs[i][3];
        out[800+oc]  = c_score[i];
        out[1000+oc] = (float)bcls[i];
      }
      ++oc;
      rem[0]|=supp[i][0]; rem[1]|=supp[i][1]; rem[2]|=supp[i][2]; rem[3]|=supp[i][3];
    }
  }
}

extern "C" void kernel_launch(void* const* d_in, const int* in_sizes, int n_in,
                              void* d_out, int out_size, void* d_ws, size_t ws_size,
                              hipStream_t stream) {
  const float* F     = (const float*)d_in[0];
  const float* props = (const float*)d_in[1];
  const float* wfc   = (const float*)d_in[2];
  const float* bfc   = (const float*)d_in[3];
  const float* wcls  = (const float*)d_in[4];
  const float* bcls  = (const float*)d_in[5];
  const float* wbox  = (const float*)d_in[6];
  const float* bbox  = (const float*)d_in[7];
  float* out = (float*)d_out;
  char* wsb  = (char*)d_ws;

  const size_t abytes = (size_t)N_PROP * K_DIM * 2;      // per bf16 plane
  ushort_t* Ahi = (ushort_t*)wsb;
  ushort_t* Alo = (ushort_t*)(wsb + abytes);
  float* X  = (float*)(wsb + 2*abytes);                   // 262144
  float* SC = X + 262144;                                 // 20480
  float* DL = SC + 20480;                                 // 81920
  float* KM = DL + 81920;                                 // 256
  float* P  = KM + 256;                                   // ksplit * 1 MB (floats)
  const size_t fixed = 2*abytes + (size_t)(262144 + 20480 + 81920 + 256) * 4;
  if (ws_size < fixed + 2u*1048576u) {
    (void)hipMemsetAsync(d_out, 0x7F, (size_t)out_size*sizeof(float), stream);
    return;
  }
  int ksplit = (int)((ws_size - fixed) / ((size_t)N_PROP * D_HID * 4));
  if (ksplit > 64) ksplit = 64;
  if (ksplit >= 8) ksplit &= ~7;            // multiple of 8 -> bijective XCD swizzle
  const int steps_per = (6272 + ksplit - 1) / ksplit;
  const int nwg = 4 * ksplit;

  roi_kernel   <<<dim3(8, N_PROP),    256, 0, stream>>>(F, props, Ahi, Alo);
  mfma_gemm    <<<nwg,                512, 0, stream>>>(Ahi, Alo, wfc, P, steps_per, nwg);
  reduce_kernel<<<256,                256, 0, stream>>>(P, X, ksplit);
  heads_kernel <<<N_PROP,             256, 0, stream>>>(X, bfc, wcls, bcls, wbox, bbox, SC, DL, KM);
  detect_kernel<<<1,                  256, 0, stream>>>(SC, DL, props, KM, out);
}

// Round 21
// 794.775 us; speedup vs baseline: 1.4990x; 1.0037x over previous
//
#include <hip/hip_runtime.h>
#include <math.h>

#define N_PROP 256
#define NUM_CLASS 80
#define H_FEAT 50
#define W_FEAT 80
#define K_DIM 200704        // 1024*14*14
#define D_HID 1024
#define SPATIAL_SCALE 0.0625f
#define SCALE_CLAMP 4.135166556742356f   // log(1000/16)
#define IMG_W_F 1280.0f
#define IMG_H_F 800.0f

typedef unsigned short ushort_t;
typedef __attribute__((ext_vector_type(8))) short short8v;       // 8 bf16 = 4 VGPR
typedef __attribute__((ext_vector_type(16))) float f32x16;       // 32x32 acc
typedef __attribute__((ext_vector_type(4))) float f32x4v;        // ext-vector float4
typedef __attribute__((ext_vector_type(4))) unsigned short ushort4v;
typedef __attribute__((ext_vector_type(2))) unsigned short ushort2v;

__device__ __forceinline__ unsigned short f2bf(float f) {
  unsigned int u = __builtin_bit_cast(unsigned int, f);
  u += 0x7FFFu + ((u >> 16) & 1u);                 // RNE
  return (unsigned short)(u >> 16);
}
__device__ __forceinline__ float bf2f(unsigned short h) {
  unsigned int u = ((unsigned int)h) << 16;
  return __builtin_bit_cast(float, u);
}

// ---------------- RoIAlign -> A as bf16 hi/lo planes (r13 verbatim) ----------------
__global__ void roi_kernel(const float* __restrict__ F, const float* __restrict__ props,
                           ushort_t* __restrict__ Ahi, ushort_t* __restrict__ Alo) {
  const int tid = threadIdx.x;
  const int m = blockIdx.y;
  const int cg = blockIdx.x;                 // channel group of 128
  __shared__ float w00[196], w01[196], w10[196], w11[196];
  __shared__ int o00[196], o01[196], o10[196], o11[196];
  const float x1s = props[m*4+0]*SPATIAL_SCALE;
  const float y1s = props[m*4+1]*SPATIAL_SCALE;
  const float x2s = props[m*4+2]*SPATIAL_SCALE;
  const float y2s = props[m*4+3]*SPATIAL_SCALE;
  const float bwf = fmaxf(x2s-x1s, 1.0f) / 14.0f;
  const float bhf = fmaxf(y2s-y1s, 1.0f) / 14.0f;
  if (tid < 196) {
    int ph = tid / 14, pw = tid - ph*14;
    float X = x1s + (pw + 0.5f)*bwf;
    float Y = y1s + (ph + 0.5f)*bhf;
    bool valid = (Y >= -1.0f) && (Y <= (float)H_FEAT) && (X >= -1.0f) && (X <= (float)W_FEAT);
    float x = fminf(fmaxf(X, 0.0f), (float)(W_FEAT-1));
    float y = fminf(fmaxf(Y, 0.0f), (float)(H_FEAT-1));
    float xf = floorf(x), yf = floorf(y);
    int ix0 = (int)xf, iy0 = (int)yf;
    int ix1 = min(ix0+1, W_FEAT-1), iy1 = min(iy0+1, H_FEAT-1);
    float lx = x-xf, ly = y-yf, hx = 1.0f-lx, hy = 1.0f-ly;
    float v = valid ? 1.0f : 0.0f;
    w00[tid] = hy*hx*v; w01[tid] = hy*lx*v; w10[tid] = ly*hx*v; w11[tid] = ly*lx*v;
    o00[tid] = iy0*W_FEAT+ix0; o01[tid] = iy0*W_FEAT+ix1;
    o10[tid] = iy1*W_FEAT+ix0; o11[tid] = iy1*W_FEAT+ix1;
  }
  __syncthreads();
  const int base_c = cg*128;
  const size_t rowbase = (size_t)m*K_DIM + (size_t)base_c*196;
  for (int it = 0; it < 49; ++it) {          // 128*196/(256*2)
    int i2 = it*512 + tid*2;                 // even; pair never crosses channel (196 even)
    int c = i2 / 196;
    int b = i2 - c*196;
    const float* f = F + (size_t)(base_c + c)*4000;
    float v0 = w00[b]*f[o00[b]] + w01[b]*f[o01[b]] + w10[b]*f[o10[b]] + w11[b]*f[o11[b]];
    float v1 = w00[b+1]*f[o00[b+1]] + w01[b+1]*f[o01[b+1]] + w10[b+1]*f[o10[b+1]] + w11[b+1]*f[o11[b+1]];
    unsigned short h0 = f2bf(v0), h1 = f2bf(v1);
    ushort2v hv; hv[0] = h0; hv[1] = h1;
    ushort2v lv; lv[0] = f2bf(v0 - bf2f(h0)); lv[1] = f2bf(v1 - bf2f(h1));
    *(ushort2v*)&Ahi[rowbase + i2] = hv;
    *(ushort2v*)&Alo[rowbase + i2] = lv;
  }
}

// ------- split-bf16 MFMA GEMM, 256x256 tile, deep counted-vmcnt pipeline -------
// r13 skeleton; A: 4 buffers (depth-3 glds), B: 2 LDS buffers + 2 register sets (depth-2).
// Steady state: 12 loads outstanding, wait vmcnt(6) per half-step, never drains to 0.
// A buf (8192 ushorts each @0/8192/16384/24576): plane(2)*4096 + kb(2)*2048 + row(256)*8
// B buf (8192 ushorts each @32768/40960): plane(2)*4096 + kbh(2)*2048 + scol(256)*8 + sub
__global__ __launch_bounds__(512, 2) void mfma_gemm(
    const ushort_t* __restrict__ Ahi, const ushort_t* __restrict__ Alo,
    const float* __restrict__ B, float* __restrict__ P, int steps_per, int nwg) {
  __shared__ ushort_t lds[49152];            // 96 KB
  const int tid = threadIdx.x;
  const int wv = tid >> 6, lane = tid & 63, l31 = lane & 31, lhi = lane >> 5;
  const int wm = wv >> 2, wn = wv & 3;       // 2M x 4N wave grid
  int id = blockIdx.x;
  int nid = ((nwg & 7) == 0) ? ((id & 7) * (nwg >> 3) + (id >> 3)) : id;
  const int bn = (nid & 3) * 256;
  const int z  = nid >> 2;
  const int step0 = z * steps_per;           // 32-k steps
  int steps = steps_per;
  if (step0 + steps > 6272) steps = 6272 - step0;   // may be <= 0

  f32x16 acc[4][2];
  #pragma unroll
  for (int a = 0; a < 4; ++a)
    #pragma unroll
    for (int b = 0; b < 2; ++b)
      #pragma unroll
      for (int e = 0; e < 16; ++e) acc[a][b][e] = 0.0f;

  if (steps > 0) {
    const int H = steps * 2;                 // 16-k halves (always even, >= 2)
    const ushort_t* asrc[2];
    #pragma unroll
    for (int i = 0; i < 2; ++i) {
      int s = i*512 + tid;
      int plane = s >> 9, kb = (s >> 8) & 1, row = s & 255;
      const ushort_t* basep = plane ? Alo : Ahi;
      asrc[i] = basep + (size_t)row * K_DIM + step0*32 + kb*8;
    }
    const int p = tid >> 6, c4 = tid & 63;
    const bool bstage = (tid < 256);
    const float* bsrc = B + (size_t)(step0*32 + 4*p) * D_HID + bn + c4*4;
    const unsigned bkbh = (unsigned)(p >> 1) * 2048u, bsub = (unsigned)((p & 1) * 4);

    #define STAGE_A(aoff) do { \
      _Pragma("unroll") \
      for (int i = 0; i < 2; ++i) { \
        __builtin_amdgcn_global_load_lds(asrc[i], &lds[(aoff) + (unsigned)(i*512 + tid)*8u], 16, 0, 0); \
        asrc[i] += 16; } \
    } while (0)

    #define LOAD_B(s0,s1,s2,s3) do { \
      if (bstage) { \
        s0 = __builtin_nontemporal_load((const f32x4v*)(bsrc)); \
        s1 = __builtin_nontemporal_load((const f32x4v*)(bsrc + D_HID)); \
        s2 = __builtin_nontemporal_load((const f32x4v*)(bsrc + 2*D_HID)); \
        s3 = __builtin_nontemporal_load((const f32x4v*)(bsrc + 3*D_HID)); \
      } \
      bsrc += 16 * D_HID; \
    } while (0)

    #define WRITE_B(boff,s0,s1,s2,s3) do { \
      if (bstage) { \
        _Pragma("unroll") \
        for (int cc = 0; cc < 4; ++cc) { \
          float g0 = s0[cc], g1 = s1[cc], g2 = s2[cc], g3 = s3[cc]; \
          ushort4v hv, lv; \
          hv[0]=f2bf(g0); lv[0]=f2bf(g0-bf2f(hv[0])); \
          hv[1]=f2bf(g1); lv[1]=f2bf(g1-bf2f(hv[1])); \
          hv[2]=f2bf(g2); lv[2]=f2bf(g2-bf2f(hv[2])); \
          hv[3]=f2bf(g3); lv[3]=f2bf(g3-bf2f(hv[3])); \
          int col = c4*4 + cc, scol = col ^ ((col>>3)&7); \
          unsigned idx = (boff) + bkbh + (unsigned)scol*8u + bsub; \
          *(ushort4v*)&lds[idx] = hv; \
          *(ushort4v*)&lds[idx + 4096] = lv; \
        } \
      } \
    } while (0)

    #define COMPUTE(aoff, boff) do { \
      short8v ah[4], al[4], bh[2], bl[2]; \
      _Pragma("unroll") \
      for (int ms = 0; ms < 4; ++ms) { \
        unsigned ai = (aoff) + (unsigned)(lhi*2048 + (wm*128 + ms*32 + l31)*8); \
        ah[ms] = *(const short8v*)&lds[ai]; \
        al[ms] = *(const short8v*)&lds[ai + 4096]; \
      } \
      _Pragma("unroll") \
      for (int ns = 0; ns < 2; ++ns) { \
        int col = wn*64 + ns*32 + l31, scol = col ^ ((col>>3)&7); \
        unsigned bi = (boff) + (unsigned)(lhi*2048 + scol*8); \
        bh[ns] = *(const short8v*)&lds[bi]; \
        bl[ns] = *(const short8v*)&lds[bi + 4096]; \
      } \
      __builtin_amdgcn_s_setprio(1); \
      _Pragma("unroll") \
      for (int ms = 0; ms < 4; ++ms) \
        _Pragma("unroll") \
        for (int ns = 0; ns < 2; ++ns) { \
          acc[ms][ns] = __builtin_amdgcn_mfma_f32_32x32x16_bf16(ah[ms], bh[ns], acc[ms][ns], 0, 0, 0); \
          acc[ms][ns] = __builtin_amdgcn_mfma_f32_32x32x16_bf16(ah[ms], bl[ns], acc[ms][ns], 0, 0, 0); \
          acc[ms][ns] = __builtin_amdgcn_mfma_f32_32x32x16_bf16(al[ms], bh[ns], acc[ms][ns], 0, 0, 0); \
        } \
      __builtin_amdgcn_s_setprio(0); \
    } while (0)

    f32x4v x0, x1, x2, x3;   // B register set 0 (even halves' loads)
    f32x4v y0, y1, y2, y3;   // B register set 1 (odd halves' loads)
    // ---- prologue ----
    LOAD_B(x0,x1,x2,x3);               // B(0): 4 vm
    STAGE_A(0u);                       // A(0): 2 vm
    STAGE_A(8192u);                    // A(1): 2 vm
    asm volatile("s_waitcnt vmcnt(4)" ::: "memory");   // B(0) regs ready
    __builtin_amdgcn_sched_barrier(0);
    WRITE_B(32768u, x0,x1,x2,x3);      // B(0) -> bufB0
    LOAD_B(y0,y1,y2,y3);               // B(1): 4 vm   (H >= 2 always)
    if (H > 2) {
      STAGE_A(16384u);                 // A(2): 2 vm
      asm volatile("s_waitcnt vmcnt(8)" ::: "memory"); // A(0) done
    } else {
      asm volatile("s_waitcnt vmcnt(6)" ::: "memory"); // A(0) done
    }
    asm volatile("s_waitcnt lgkmcnt(0)" ::: "memory");
    __builtin_amdgcn_s_barrier();
    __builtin_amdgcn_sched_barrier(0);

    unsigned aC = 0u, aN = 8192u, aNN = 16384u, aNNN = 24576u;
    for (int h = 0; h < H; h += 2) {
      { // even half h: compute bufB0; load B(h+2)->set0; write B(h+1)->bufB1
        const int rem = H - 1 - h;
        if (rem >= 2) LOAD_B(x0,x1,x2,x3);          // B(h+2)
        if (rem >= 3) STAGE_A(aNNN);                // A(h+3)
        COMPUTE(aC, 32768u);
        if (rem >= 2) asm volatile("s_waitcnt vmcnt(6)" ::: "memory");
        else          asm volatile("s_waitcnt vmcnt(0)" ::: "memory");
        __builtin_amdgcn_sched_barrier(0);
        if (rem >= 1) WRITE_B(40960u, y0,y1,y2,y3); // B(h+1) -> bufB1
        asm volatile("s_waitcnt lgkmcnt(0)" ::: "memory");
        __builtin_amdgcn_s_barrier();
        __builtin_amdgcn_sched_barrier(0);
        unsigned t = aC; aC = aN; aN = aNN; aNN = aNNN; aNNN = t;
      }
      if (h + 1 < H) { // odd half h+1: compute bufB1; load B(h+3)->set1; write B(h+2)->bufB0
        const int rem = H - 2 - h;
        if (rem >= 2) LOAD_B(y0,y1,y2,y3);          // B(h+3)
        if (rem >= 3) STAGE_A(aNNN);                // A(h+4)
        COMPUTE(aC, 40960u);
        if (rem >= 2) asm volatile("s_waitcnt vmcnt(6)" ::: "memory");
        else          asm volatile("s_waitcnt vmcnt(0)" ::: "memory");
        __builtin_amdgcn_sched_barrier(0);
        if (rem >= 1) WRITE_B(32768u, x0,x1,x2,x3); // B(h+2) -> bufB0
        asm volatile("s_waitcnt lgkmcnt(0)" ::: "memory");
        __builtin_amdgcn_s_barrier();
        __builtin_amdgcn_sched_barrier(0);
        unsigned t = aC; aC = aN; aN = aNN; aNN = aNNN; aNNN = t;
      }
    }
    #undef STAGE_A
    #undef LOAD_B
    #undef WRITE_B
    #undef COMPUTE
  }
  // write partial tile: D layout col=lane&31, row=(r&3)+8*(r>>2)+4*(lane>>5)
  float* Pp = P + (size_t)z * (N_PROP * D_HID);
  #pragma unroll
  for (int ms = 0; ms < 4; ++ms)
    #pragma unroll
    for (int ns = 0; ns < 2; ++ns)
      #pragma unroll
      for (int r = 0; r < 16; ++r) {
        int row = wm*128 + ms*32 + (r & 3) + 8*(r >> 2) + 4*lhi;
        int col = bn + wn*64 + ns*32 + l31;
        __builtin_nontemporal_store(acc[ms][ns][r], &Pp[(size_t)row * D_HID + col]);
      }
}

__global__ void reduce_kernel(const float* __restrict__ P, float* __restrict__ X, int ksplit) {
  int i = blockIdx.x*256 + threadIdx.x;    // quad index, 65536 total
  f32x4v s = {0.0f, 0.0f, 0.0f, 0.0f};
  const f32x4v* P4 = (const f32x4v*)P;
  for (int r = 0; r < ksplit; ++r) s += P4[(size_t)r*65536 + i];
  ((f32x4v*)X)[i] = s;
}

// ---------------- heads + softmax + ORDER KEY (r13 verbatim) ----------------
__global__ void heads_kernel(const float* __restrict__ X, const float* __restrict__ bfc,
                             const float* __restrict__ wcls, const float* __restrict__ bcls,
                             const float* __restrict__ wbox, const float* __restrict__ bbox,
                             float* __restrict__ scores, float* __restrict__ deltas,
                             float* __restrict__ keym) {
  const int tid = threadIdx.x, m = blockIdx.x;
  __shared__ float xs[1024];
  __shared__ float lg[81];
  __shared__ float red[2];
  #pragma unroll
  for (int r = 0; r < 4; ++r) {
    int k = r*256 + tid;
    xs[k] = X[m*1024 + k] + bfc[k];
  }
  __syncthreads();
  for (int j = tid; j < 401; j += 256) {
    if (j < 81) {
      const float* w = wcls + j;
      float accv = bcls[j];
      #pragma unroll 8
      for (int k = 0; k < 1024; ++k) accv = fmaf(xs[k], w[(size_t)k*81], accv);
      lg[j] = accv;
    } else {
      int jb = j - 81;
      const float* w = wbox + jb;
      float accv = bbox[jb];
      #pragma unroll 8
      for (int k = 0; k < 1024; ++k) accv = fmaf(xs[k], w[(size_t)k*320], accv);
      deltas[m*320 + jb] = accv;
    }
  }
  __syncthreads();
  if (tid == 0) {
    float mx = lg[0]; int amax = 0;
    for (int j = 1; j < 81; ++j) if (lg[j] > mx) { mx = lg[j]; amax = j; }
    float sm = 0.0f;
    for (int j = 0; j < 81; ++j) sm += expf(lg[j]-mx);
    float m2 = -1e30f;
    for (int j = 0; j < 81; ++j) if (j != amax) m2 = fmaxf(m2, lg[j]);
    float s2 = 0.0f;
    for (int j = 0; j < 81; ++j) if (j != amax) s2 += expf(lg[j]-m2);
    keym[m] = (m2 - mx) + logf(s2);
    red[0] = mx; red[1] = sm;
  }
  __syncthreads();
  if (tid < 80) scores[m*80 + tid] = expf(lg[tid+1]-red[0]) / red[1];
}

// ---------------- selection + NMS + f32 output (r13 verbatim) ----------------
__global__ void detect_kernel(const float* __restrict__ scores, const float* __restrict__ deltas,
                              const float* __restrict__ props, const float* __restrict__ keym,
                              float* __restrict__ out) {
  const int tid = threadIdx.x;
  __shared__ int s_cnt;
  __shared__ float g_key[256];
  __shared__ float g_score[256];
  __shared__ int   g_idx[256];
  __shared__ float c_score[256];
  __shared__ int   c_idx[256];
  __shared__ float bxs[256][4];
  __shared__ int   bcls[256];
  __shared__ unsigned long long supp[256][4];
  if (tid == 0) s_cnt = 0;
  g_key[tid] = 1e30f; g_score[tid] = -1.0f; g_idx[tid] = 0x7FFFFFFF;
  c_score[tid] = -1.0f; c_idx[tid] = 0x7FFFFFFF;
  bxs[tid][0] = bxs[tid][1] = bxs[tid][2] = bxs[tid][3] = 0.0f;
  bcls[tid] = 0;
  __syncthreads();
  for (int t = 0; t < 80; ++t) {
    int i = t*256 + tid;
    float s = scores[i];
    if (s > 0.5f) {
      int p = atomicAdd(&s_cnt, 1);
      if (p < 256) { g_score[p] = s; g_idx[p] = i; g_key[p] = keym[i/80]; }
    }
  }
  __syncthreads();
  const int C = min(s_cnt, 256);
  if (tid < C) {
    float kt = g_key[tid]; int si = g_idx[tid]; float st = g_score[tid];
    int rank = 0;
    for (int u = 0; u < C; ++u) {
      float ku = g_key[u]; int iu = g_idx[u];
      if ((ku < kt) || (ku == kt && iu < si)) ++rank;
    }
    c_score[rank] = st; c_idx[rank] = si;
  }
  __syncthreads();
  if (tid < C) {
    int fi = c_idx[tid];
    int m = fi / 80, j = fi - m*80;
    float px1 = props[m*4+0], py1 = props[m*4+1], px2 = props[m*4+2], py2 = props[m*4+3];
    float w = px2-px1, h = py2-py1;
    float cx = px1 + 0.5f*w, cy = py1 + 0.5f*h;
    const float* d = deltas + m*320 + j*4;
    float dx = d[0]/10.0f, dy = d[1]/10.0f;
    float dw = fminf(d[2]/5.0f, SCALE_CLAMP), dh = fminf(d[3]/5.0f, SCALE_CLAMP);
    float pcx = dx*w + cx, pcy = dy*h + cy;
    float pw = expf(dw)*w, ph = expf(dh)*h;
    bxs[tid][0] = fminf(fmaxf(pcx - 0.5f*pw, 0.0f), IMG_W_F);
    bxs[tid][1] = fminf(fmaxf(pcy - 0.5f*ph, 0.0f), IMG_H_F);
    bxs[tid][2] = fminf(fmaxf(pcx + 0.5f*pw, 0.0f), IMG_W_F);
    bxs[tid][3] = fminf(fmaxf(pcy + 0.5f*ph, 0.0f), IMG_H_F);
    bcls[tid] = j;
  }
  __syncthreads();
  unsigned long long row[4] = {0,0,0,0};
  if (tid < C) {
    float ax1=bxs[tid][0], ay1=bxs[tid][1], ax2=bxs[tid][2], ay2=bxs[tid][3];
    float aarea = fmaxf(ax2-ax1,0.f)*fmaxf(ay2-ay1,0.f);
    int acl = bcls[tid];
    for (int j2 = tid+1; j2 < C; ++j2) {
      if (bcls[j2] != acl) continue;
      float b1=bxs[j2][0], b2=bxs[j2][1], b3=bxs[j2][2], b4=bxs[j2][3];
      float barea = fmaxf(b3-b1,0.f)*fmaxf(b4-b2,0.f);
      float iw = fmaxf(fminf(ax2,b3) - fmaxf(ax1,b1), 0.f);
      float ih = fmaxf(fminf(ay2,b4) - fmaxf(ay1,b2), 0.f);
      float inter = iw*ih;
      float iou = inter / fmaxf(aarea + barea - inter, 1e-9f);
      if (iou > 0.7f) row[j2>>6] |= (1ull << (j2 & 63));
    }
  }
  supp[tid][0]=row[0]; supp[tid][1]=row[1]; supp[tid][2]=row[2]; supp[tid][3]=row[3];
  __syncthreads();
  for (int i = tid; i < 1200; i += 256) out[i] = (i >= 1000) ? -1.0f : 0.0f;
  __syncthreads();
  if (tid == 0) {
    unsigned long long rem[4] = {0,0,0,0};
    int oc = 0;
    for (int i = 0; i < C; ++i) {
      if ((rem[i>>6] >> (i & 63)) & 1ull) continue;
      if (oc < 200) {
        out[oc*4+0]=bxs[i][0]; out[oc*4+1]=bxs[i][1]; out[oc*4+2]=bxs[i][2]; out[oc*4+3]=bxs[i][3];
        out[800+oc]  = c_score[i];
        out[1000+oc] = (float)bcls[i];
      }
      ++oc;
      rem[0]|=supp[i][0]; rem[1]|=supp[i][1]; rem[2]|=supp[i][2]; rem[3]|=supp[i][3];
    }
  }
}

extern "C" void kernel_launch(void* const* d_in, const int* in_sizes, int n_in,
                              void* d_out, int out_size, void* d_ws, size_t ws_size,
                              hipStream_t stream) {
  const float* F     = (const float*)d_in[0];
  const float* props = (const float*)d_in[1];
  const float* wfc   = (const float*)d_in[2];
  const float* bfc   = (const float*)d_in[3];
  const float* wcls  = (const float*)d_in[4];
  const float* bcls  = (const float*)d_in[5];
  const float* wbox  = (const float*)d_in[6];
  const float* bbox  = (const float*)d_in[7];
  float* out = (float*)d_out;
  char* wsb  = (char*)d_ws;

  const size_t abytes = (size_t)N_PROP * K_DIM * 2;      // per bf16 plane
  ushort_t* Ahi = (ushort_t*)wsb;
  ushort_t* Alo = (ushort_t*)(wsb + abytes);
  float* X  = (float*)(wsb + 2*abytes);                   // 262144
  float* SC = X + 262144;                                 // 20480
  float* DL = SC + 20480;                                 // 81920
  float* KM = DL + 81920;                                 // 256
  float* P  = KM + 256;                                   // ksplit * 1 MB (floats)
  const size_t fixed = 2*abytes + (size_t)(262144 + 20480 + 81920 + 256) * 4;
  if (ws_size < fixed + 2u*1048576u) {
    (void)hipMemsetAsync(d_out, 0x7F, (size_t)out_size*sizeof(float), stream);
    return;
  }
  int ksplit = (int)((ws_size - fixed) / ((size_t)N_PROP * D_HID * 4));
  if (ksplit > 64) ksplit = 64;
  if (ksplit >= 8) ksplit &= ~7;            // multiple of 8 -> bijective XCD swizzle
  const int steps_per = (6272 + ksplit - 1) / ksplit;
  const int nwg = 4 * ksplit;

  roi_kernel   <<<dim3(8, N_PROP),    256, 0, stream>>>(F, props, Ahi, Alo);
  mfma_gemm    <<<nwg,                512, 0, stream>>>(Ahi, Alo, wfc, P, steps_per, nwg);
  reduce_kernel<<<256,                256, 0, stream>>>(P, X, ksplit);
  heads_kernel <<<N_PROP,             256, 0, stream>>>(X, bfc, wcls, bcls, wbox, bbox, SC, DL, KM);
  detect_kernel<<<1,                  256, 0, stream>>>(SC, DL, props, KM, out);
}